// Round 12
// baseline (157.716 us; speedup 1.0000x reference)
//
#include <hip/hip_runtime.h>
#include <cmath>

#define BBATCH 8
#define NN 128
#define DD 128      // IN_DIM
#define CC 64       // IN_DIM_E
#define HH 8
#define KK 64
#define HK 512
#define ROWS (BBATCH*NN)     // 1024
#define MATSZ (ROWS*HK)      // 524288 elements per projection matrix

typedef __attribute__((ext_vector_type(8))) short sh8;    // 8 bf16 = 4 VGPRs
typedef __attribute__((ext_vector_type(4))) float f32x4;  // MFMA C/D

static __device__ __forceinline__ unsigned short f2bf(float f) {
    union { float f; unsigned u; } v; v.f = f;
    unsigned r = v.u + 0x7fffu + ((v.u >> 16) & 1u);   // RNE
    return (unsigned short)(r >> 16);
}
static __device__ __forceinline__ float bf2f(unsigned short u) {
    union { unsigned u; float f; } v; v.u = ((unsigned)u) << 16;
    return v.f;
}

// ws layout (floats):
//   [0 .. M)      Qh fp32 [b*n][hk]
//   [M .. 2M)     Q2 fp32 [b*n][hk]
//   [2M .. 3M)    Vh fp32 [b*n][hk]
//   ushort* U = (ushort*)(ws + 3M):
//     [0 .. M)     Kt1 bf16 [b][h][j][k'] k-permuted: k' = q4*16 + mb*4 + reg
//     [M .. 2M)    Kt2 bf16 same layout   (both pre-scaled by K^-0.5)
//     [2M .. +64K) Wfrag bf16 [2][8 h][8 frag][64 lane][8]  (A-operand order)

// ---------------- Kernel 1: projections + W fragment conversion ----------------
__global__ __launch_bounds__(256) void proj_kernel(
    const float* __restrict__ h,
    const float* __restrict__ Wq, const float* __restrict__ Wk,
    const float* __restrict__ Wv, const float* __restrict__ Wq2,
    const float* __restrict__ Wk2,
    const float* __restrict__ We, const float* __restrict__ We2,
    float* __restrict__ ws)
{
    const int t  = threadIdx.x;
    const int bx = blockIdx.x;
    const int by = blockIdx.y;

    if (by >= 40) {
        // ---- W -> A-fragment-order bf16 ----
        const int v = by - 40;
        const float* W = v ? We2 : We;
        unsigned short* Wfrag = (unsigned short*)(ws + 3*(size_t)MATSZ) + 2*(size_t)MATSZ
                              + (size_t)v * 32768;
        const int g   = bx * 256 + t;     // 0..4095
        const int c   = g >> 6;           // 0..63
        const int sub = g & 63;
        const int hh  = sub >> 3;
        const int k0  = (sub & 7) * 8;
        float4 w0 = *(const float4*)(W + (size_t)c*HK + hh*KK + k0);
        float4 w1 = *(const float4*)(W + (size_t)c*HK + hh*KK + k0 + 4);
        float wv[8] = {w0.x,w0.y,w0.z,w0.w,w1.x,w1.y,w1.z,w1.w};
        const int cb = c >> 5, g4 = (c >> 3) & 3, jj = c & 7;
        #pragma unroll
        for (int q = 0; q < 8; ++q) {
            int k  = k0 + q;
            int mb = k >> 4, m = k & 15;
            Wfrag[(size_t)hh*4096 + (mb*2+cb)*512 + (g4*16+m)*8 + jj] = f2bf(wv[q]);
        }
        return;
    }

    __shared__ float As[64*136];
    __shared__ float Bs[128*64];
    const int m    = by >> 3;
    const int col0 = (by & 7) * 64;
    const float* W = (m==0)?Wq:(m==1)?Wk:(m==2)?Wv:(m==3)?Wq2:Wk2;
    const float scale = (m==1 || m==4) ? 0.125f : 1.0f;
    const int row0 = bx * 64;

    for (int r = 0; r < 8; ++r) {
        int idx = t + 256*r;
        int row = idx >> 5;
        int c4  = idx & 31;
        float4 v = ((const float4*)(h + (size_t)(row0+row)*DD))[c4];
        ((float4*)(As + row*136))[c4] = v;
    }
    for (int r = 0; r < 8; ++r) {
        int idx = t + 256*r;
        int kk = idx >> 4;
        int c4 = idx & 15;
        ((float4*)Bs)[idx] = ((const float4*)(W + (size_t)kk*HK + col0))[c4];
    }
    __syncthreads();

    const int tx = t & 15, ty = t >> 4;
    float acc[4][4] = {};
    #pragma unroll 2
    for (int k4 = 0; k4 < 32; ++k4) {
        float a4[4][4], b4[4][4];
        #pragma unroll
        for (int ii = 0; ii < 4; ++ii)
            *(float4*)a4[ii] = *(const float4*)(As + (ty*4+ii)*136 + k4*4);
        #pragma unroll
        for (int kk = 0; kk < 4; ++kk)
            *(float4*)b4[kk] = ((const float4*)Bs)[(k4*4+kk)*16 + tx];
        #pragma unroll
        for (int ii = 0; ii < 4; ++ii)
            #pragma unroll
            for (int kk = 0; kk < 4; ++kk) {
                acc[ii][0] += a4[ii][kk]*b4[kk][0];
                acc[ii][1] += a4[ii][kk]*b4[kk][1];
                acc[ii][2] += a4[ii][kk]*b4[kk][2];
                acc[ii][3] += a4[ii][kk]*b4[kk][3];
            }
    }

    const int hh = by & 7;   // head index (col0 = hh*64)
    if (m == 1 || m == 4) {
        // K -> bf16 [b][h][j][k'], k' = q4*16 + mb*4 + reg  (q4=tx&3, mb=tx>>2)
        unsigned short* Kt = (unsigned short*)(ws + 3*(size_t)MATSZ)
                           + (m==4 ? (size_t)MATSZ : 0);
        const int kperm = (tx & 3)*16 + (tx >> 2)*4;
        #pragma unroll
        for (int ii = 0; ii < 4; ++ii) {
            int r = row0 + ty*4 + ii;
            int bb = r >> 7, j = r & 127;
            ushort4 u;
            u.x = f2bf(acc[ii][0]*scale); u.y = f2bf(acc[ii][1]*scale);
            u.z = f2bf(acc[ii][2]*scale); u.w = f2bf(acc[ii][3]*scale);
            *(ushort4*)(Kt + ((size_t)(bb*HH+hh)*NN + j)*KK + kperm) = u;
        }
    } else {
        float* outp = ws + (m==0 ? 0 : (m==3 ? (size_t)MATSZ : 2*(size_t)MATSZ));
        #pragma unroll
        for (int ii = 0; ii < 4; ++ii) {
            int r = row0 + ty*4 + ii;
            float4 v = make_float4(acc[ii][0], acc[ii][1], acc[ii][2], acc[ii][3]);
            ((float4*)(outp + (size_t)r*HK + col0))[tx] = v;
        }
    }
}

// ---------------- Kernel 2: adj-sorted single-variant MFMA attn (TI=2) ----------------
// Columns sorted by adj per (b,i): each 16-col tile computes only its variant.
// 8 units (heads); per-lane K/Q variant select; straddle tile does both + cndmask.
__global__ __launch_bounds__(256, 2) void attn_kernel(
    const float* __restrict__ e, const float* __restrict__ k_RW,
    const float* __restrict__ mask, const int* __restrict__ adj,
    const float* __restrict__ ws, float* __restrict__ out)
{
    __shared__ float q_s[2*2*HK];     // 8 KB [v][il][hk]
    __shared__ float sc_s[2*HH*NN];   // 8 KB [il][h][j]
    __shared__ float kwm_s[2*NN];
    __shared__ int   jp_s[2][2][NN];  // [il][adj][pos]
    __shared__ int   cnt_s[2][2];

    const int t    = threadIdx.x;
    const int blk  = blockIdx.x;          // 512 blocks
    const int b    = blk & 7;             // XCD-pinned batch
    const int i0   = (blk >> 3) * 2;
    const int lane = t & 63;
    const int w    = t >> 6;
    const int jl   = lane & 15;
    const int q4   = lane >> 4;
    const int kq   = q4 * 4;

    const float* Vh = ws + 2*(size_t)MATSZ;
    const unsigned short* U   = (const unsigned short*)(ws + 3*(size_t)MATSZ);
    const unsigned short* Wfg = U + 2*(size_t)MATSZ;

    if (t < 4) ((int*)cnt_s)[t] = 0;
    __syncthreads();

    // ---- phase 0a: adj-sort (LDS atomics) + kwm + Q ----
    {
        const int il = t >> 7, j = t & 127;
        kwm_s[t] = k_RW[(size_t)(b*NN + i0 + il)*NN + j] * mask[b*NN + j];
        int a = (adj[(size_t)(b*NN + i0 + il)*NN + j] != 0) ? 1 : 0;
        int pos = atomicAdd(&cnt_s[il][a], 1);
        jp_s[il][a][pos] = j;
    }
    #pragma unroll
    for (int r = 0; r < 8; ++r) {   // Q: 2048 floats
        int idx = t + 256*r;
        int v  = idx >> 10;
        int il = (idx >> 9) & 1;
        int hk = idx & 511;
        q_s[idx] = ws[(size_t)v*MATSZ + (size_t)(b*NN + i0 + il)*HK + hk];
    }
    const float maskI0 = mask[b*NN + i0];
    const float maskI1 = mask[b*NN + i0 + 1];
    __syncthreads();

    // ---- phase 0b: per-lane sorted column, variant, tile kind ----
    const int n1_0 = cnt_s[0][1], n1_1 = cnt_s[1][1];
    int jcolR[2][2], vlR[2][2], vtR[2][2];
    #pragma unroll
    for (int il = 0; il < 2; ++il) {
        const int n1 = il ? n1_1 : n1_0;
        #pragma unroll
        for (int jj = 0; jj < 2; ++jj) {
            const int p  = w*32 + jj*16 + jl;
            const int lt = (p < n1) ? 1 : 0;
            jcolR[il][jj] = lt ? jp_s[il][1][p] : jp_s[il][0][p - n1];
            vlR[il][jj]   = 1 - lt;                 // 0 -> variant1(We), 1 -> variant2
            const int base = w*32 + jj*16;
            vtR[il][jj] = (base + 16 <= n1) ? 0 : ((base >= n1) ? 1 : 2);
        }
    }
    const int prim = (w*32 + 8 < n1_0) ? 0 : 1;     // wave's pipelined W variant

    // ---- phase 0c: e-fragments (rows = sorted columns; same scatter profile) ----
    sh8 eF[2][2][2];   // [il][jj][cb]
    #pragma unroll
    for (int il = 0; il < 2; ++il) {
        const float* ep = e + (size_t)(b*NN + i0 + il) * (NN*CC);
        #pragma unroll
        for (int jj = 0; jj < 2; ++jj) {
            const int row = jcolR[il][jj];
            #pragma unroll
            for (int cb = 0; cb < 2; ++cb) {
                const int c0 = cb*32 + q4*8;
                float a0[4], a1[4];
                *(float4*)a0 = *(const float4*)(ep + (size_t)row*CC + c0);
                *(float4*)a1 = *(const float4*)(ep + (size_t)row*CC + c0 + 4);
                sh8 f;
                f[0]=(short)f2bf(a0[0]); f[1]=(short)f2bf(a0[1]);
                f[2]=(short)f2bf(a0[2]); f[3]=(short)f2bf(a0[3]);
                f[4]=(short)f2bf(a1[0]); f[5]=(short)f2bf(a1[1]);
                f[6]=(short)f2bf(a1[2]); f[7]=(short)f2bf(a1[3]);
                eF[il][jj][cb] = f;
            }
        }
    }

    sh8  aFA[8], aFB[8];
    int4 kvA[2][2][2], kvB[2][2][2];   // [il][jj][half]

#define LOADU(u_, aF_, kv_)                                                     \
    {   const int h_ = (u_);                                                    \
        const sh8* wA_ = (const sh8*)(Wfg + (size_t)prim*32768 + (size_t)h_*4096); \
        _Pragma("unroll")                                                       \
        for (int f_ = 0; f_ < 8; ++f_) aF_[f_] = wA_[f_*64 + lane];             \
        _Pragma("unroll")                                                       \
        for (int il_ = 0; il_ < 2; ++il_)                                       \
            _Pragma("unroll")                                                   \
            for (int jj_ = 0; jj_ < 2; ++jj_) {                                 \
                const unsigned short* kt_ = U + (size_t)vlR[il_][jj_]*MATSZ     \
                    + (size_t)(b*HH + h_)*(NN*KK)                               \
                    + (size_t)jcolR[il_][jj_]*KK + q4*16;                       \
                kv_[il_][jj_][0] = ((const int4*)kt_)[0];                       \
                kv_[il_][jj_][1] = ((const int4*)kt_)[1];                       \
            }                                                                   \
    }

#define COMPUTE(u_, aF_, kv_)                                                   \
    {   const int h_ = (u_);                                                    \
        _Pragma("unroll")                                                       \
        for (int il_ = 0; il_ < 2; ++il_) {                                     \
            _Pragma("unroll")                                                   \
            for (int jj_ = 0; jj_ < 2; ++jj_) {                                 \
                const int vt_ = vtR[il_][jj_];                                  \
                f32x4 acc_[4];                                                  \
                _Pragma("unroll")                                               \
                for (int mb_ = 0; mb_ < 4; ++mb_) acc_[mb_] = (f32x4){0.f,0.f,0.f,0.f}; \
                if (vt_ == prim) {                                              \
                    _Pragma("unroll")                                           \
                    for (int cb_ = 0; cb_ < 2; ++cb_) {                         \
                        sh8 bF_ = eF[il_][jj_][cb_];                            \
                        _Pragma("unroll")                                       \
                        for (int mb_ = 0; mb_ < 4; ++mb_)                       \
                            acc_[mb_] = __builtin_amdgcn_mfma_f32_16x16x32_bf16( \
                                aF_[mb_*2+cb_], bF_, acc_[mb_], 0, 0, 0);       \
                    }                                                           \
                } else if (vt_ != 2) {                                          \
                    const sh8* wx_ = (const sh8*)(Wfg + (size_t)(1-prim)*32768 + (size_t)h_*4096); \
                    sh8 ax_[8];                                                 \
                    _Pragma("unroll")                                           \
                    for (int f_ = 0; f_ < 8; ++f_) ax_[f_] = wx_[f_*64 + lane]; \
                    _Pragma("unroll")                                           \
                    for (int cb_ = 0; cb_ < 2; ++cb_) {                         \
                        sh8 bF_ = eF[il_][jj_][cb_];                            \
                        _Pragma("unroll")                                       \
                        for (int mb_ = 0; mb_ < 4; ++mb_)                       \
                            acc_[mb_] = __builtin_amdgcn_mfma_f32_16x16x32_bf16( \
                                ax_[mb_*2+cb_], bF_, acc_[mb_], 0, 0, 0);       \
                    }                                                           \
                } else {   /* straddle: both variants, per-lane merge */        \
                    f32x4 a2_[4];                                               \
                    _Pragma("unroll")                                           \
                    for (int mb_ = 0; mb_ < 4; ++mb_) a2_[mb_] = (f32x4){0.f,0.f,0.f,0.f}; \
                    const sh8* wx_ = (const sh8*)(Wfg + (size_t)(1-prim)*32768 + (size_t)h_*4096); \
                    sh8 ax_[8];                                                 \
                    _Pragma("unroll")                                           \
                    for (int f_ = 0; f_ < 8; ++f_) ax_[f_] = wx_[f_*64 + lane]; \
                    _Pragma("unroll")                                           \
                    for (int cb_ = 0; cb_ < 2; ++cb_) {                         \
                        sh8 bF_ = eF[il_][jj_][cb_];                            \
                        _Pragma("unroll")                                       \
                        for (int mb_ = 0; mb_ < 4; ++mb_) {                     \
                            acc_[mb_] = __builtin_amdgcn_mfma_f32_16x16x32_bf16( \
                                aF_[mb_*2+cb_], bF_, acc_[mb_], 0, 0, 0);       \
                            a2_[mb_] = __builtin_amdgcn_mfma_f32_16x16x32_bf16( \
                                ax_[mb_*2+cb_], bF_, a2_[mb_], 0, 0, 0);        \
                        }                                                       \
                    }                                                           \
                    const bool keep_ = (vlR[il_][jj_] == prim);                 \
                    _Pragma("unroll")                                           \
                    for (int mb_ = 0; mb_ < 4; ++mb_)                           \
                        _Pragma("unroll")                                       \
                        for (int r_ = 0; r_ < 4; ++r_)                          \
                            acc_[mb_][r_] = keep_ ? acc_[mb_][r_] : a2_[mb_][r_]; \
                }                                                               \
                const int vq_ = vlR[il_][jj_];                                  \
                const unsigned short* kp_ = (const unsigned short*)&kv_[il_][jj_][0]; \
                float p_ = 0.f;                                                 \
                _Pragma("unroll")                                               \
                for (int mb_ = 0; mb_ < 4; ++mb_) {                             \
                    float4 ql_ = *(const float4*)&q_s[(vq_*2+il_)*HK + h_*KK + mb_*16 + kq]; \
                    p_ += acc_[mb_][0] * (ql_.x * bf2f(kp_[mb_*4+0]));          \
                    p_ += acc_[mb_][1] * (ql_.y * bf2f(kp_[mb_*4+1]));          \
                    p_ += acc_[mb_][2] * (ql_.z * bf2f(kp_[mb_*4+2]));          \
                    p_ += acc_[mb_][3] * (ql_.w * bf2f(kp_[mb_*4+3]));          \
                }                                                               \
                p_ += __shfl_xor(p_, 16);                                       \
                p_ += __shfl_xor(p_, 32);                                       \
                if (lane < 16) sc_s[(il_*HH + h_)*NN + jcolR[il_][jj_]] = p_;   \
            }                                                                   \
        }                                                                       \
    }

    LOADU(0, aFA, kvA)
    LOADU(1, aFB, kvB)

    // ---- pipelined unit loop over 8 heads ----
    #pragma unroll 1
    for (int u = 0; u < 8; u += 2) {
        COMPUTE(u, aFA, kvA)
        if (u + 2 < 8) LOADU(u + 2, aFA, kvA)
        COMPUTE(u + 1, aFB, kvB)
        if (u + 3 < 8) LOADU(u + 3, aFB, kvB)
    }
    __syncthreads();

    // ---- phase 2: exp * mask_i * mask_j * k_RW (global max cancels in ratio) ----
    #pragma unroll
    for (int r = 0; r < 8; ++r) {
        int idx = t + 256*r;              // (il*8+h)*128 + j
        int il = idx >> 10;
        int j  = idx & 127;
        sc_s[idx] = __expf(sc_s[idx]) * kwm_s[il*NN + j] * (il ? maskI1 : maskI0);
    }
    __syncthreads();

    // ---- phase 3: per-(il,head) denom + weighted V (coalesced fp32 rows) ----
    for (int hp = 0; hp < 2; ++hp) {
        const int hh = w + hp*4;
        const int r0 = hh*NN, r1 = (HH + hh)*NN;
        float d0 = sc_s[r0 + lane] + sc_s[r0 + 64 + lane];
        float d1 = sc_s[r1 + lane] + sc_s[r1 + 64 + lane];
        #pragma unroll
        for (int mm = 32; mm >= 1; mm >>= 1) {
            d0 += __shfl_xor(d0, mm);
            d1 += __shfl_xor(d1, mm);
        }
        float a0 = 0.f, a1 = 0.f;
        const float* vb = Vh + (size_t)(b*NN)*HK + hh*KK + lane;
        #pragma unroll 4
        for (int j = 0; j < NN; ++j) {
            float vf = vb[(size_t)j*HK];
            a0 += sc_s[r0 + j] * vf;
            a1 += sc_s[r1 + j] * vf;
        }
        out[(size_t)(b*NN + i0    )*HK + hh*KK + lane] = a0 / fmaxf(d0, 1e-6f);
        out[(size_t)(b*NN + i0 + 1)*HK + hh*KK + lane] = a1 / fmaxf(d1, 1e-6f);
    }
#undef LOADU
#undef COMPUTE
}

extern "C" void kernel_launch(void* const* d_in, const int* in_sizes, int n_in,
                              void* d_out, int out_size, void* d_ws, size_t ws_size,
                              hipStream_t stream) {
    const float* h    = (const float*)d_in[0];
    const float* e    = (const float*)d_in[1];
    const float* kRW  = (const float*)d_in[2];
    const float* mask = (const float*)d_in[3];
    const int*   adj  = (const int*)d_in[4];
    const float* Wq   = (const float*)d_in[5];
    const float* Wk   = (const float*)d_in[6];
    const float* Wv   = (const float*)d_in[7];
    const float* We   = (const float*)d_in[8];
    const float* Wq2  = (const float*)d_in[9];
    const float* Wk2  = (const float*)d_in[10];
    const float* We2  = (const float*)d_in[11];
    float* out = (float*)d_out;
    float* ws  = (float*)d_ws;   // 3*2MB f32 + 2*1MB bf16 + 128KB Wfrag ~= 8.2MB

    proj_kernel<<<dim3(16, 42), 256, 0, stream>>>(h, Wq, Wk, Wv, Wq2, Wk2, We, We2, ws);
    attn_kernel<<<dim3(512), 256, 0, stream>>>(e, kRW, mask, adj, ws, out);
}